// Round 4
// baseline (607.574 us; speedup 1.0000x reference)
//
#include <hip/hip_runtime.h>
#include <hip/hip_cooperative_groups.h>

namespace cg = cooperative_groups;

#define B_ 16
#define T_ 4096
#define D_ 768
#define NBOX 1024
#define MAXBB 128
#define DDETR 256

typedef unsigned short u16;
typedef short bf16x8 __attribute__((ext_vector_type(8)));
typedef float f32x4 __attribute__((ext_vector_type(4)));

// round-to-nearest-even fp32 -> bf16 split: f ~= hi + lo (both bf16)
__device__ __forceinline__ void split_bf(float f, u16& h, u16& l) {
    unsigned u = __builtin_bit_cast(unsigned, f);
    unsigned r = u + 0x7fffu + ((u >> 16) & 1u);
    u16 hb = (u16)(r >> 16);
    float hf = __builtin_bit_cast(float, (unsigned)hb << 16);
    float lf = f - hf;
    unsigned ul = __builtin_bit_cast(unsigned, lf);
    unsigned rl = ul + 0x7fffu + ((ul >> 16) & 1u);
    h = hb; l = (u16)(rl >> 16);
}

struct WDesc { const float* src; u16* hi; u16* lo; int N; int K; int stride; int vec; };
struct WPack8 { WDesc d[8]; };

// ================= front kernel: mean_partial || meta+viszero || pack ======
__global__ __launch_bounds__(256) void k_front(WPack8 ws,
                                               const float4* __restrict__ in4,
                                               float4* __restrict__ part4,
                                               const int* __restrict__ bboxes,
                                               int* __restrict__ cnt_g, int* __restrict__ off_g,
                                               float* __restrict__ att, f32x4* __restrict__ vis4) {
    int bx = blockIdx.x;
    int tid = threadIdx.x;
    if (bx < 1024) {
        // mean partial: block (b, c), threads 0..191 active
        if (tid >= 192) return;
        int b = bx >> 6, c = bx & 63;
        const float4* base = in4 + (size_t)b * (T_ * D_ / 4) + (size_t)c * (64 * D_ / 4);
        float4 s = {0.f, 0.f, 0.f, 0.f};
        #pragma unroll 4
        for (int r = 0; r < 64; ++r) {
            float4 v = base[(size_t)r * 192 + tid];
            s.x += v.x; s.y += v.y; s.z += v.z; s.w += v.w;
        }
        part4[(size_t)bx * 192 + tid] = s;
        return;
    }
    if (bx < 2561) {
        int mb = bx - 1024;
        if (mb > 0) {
            int idx = (mb - 1) * 256 + tid;    // < 393216
            vis4[idx] = (f32x4){0.f, 0.f, 0.f, 0.f};
            return;
        }
        __shared__ int cnt[B_];
        __shared__ int off[B_];
        if (tid < B_) cnt[tid] = 0;
        __syncthreads();
        for (int i = tid; i < NBOX; i += 256) atomicAdd(&cnt[bboxes[i * 5]], 1);
        __syncthreads();
        if (tid == 0) {
            int acc = 0;
            for (int b = 0; b < B_; ++b) { off[b] = acc; acc += cnt[b]; }
        }
        __syncthreads();
        if (tid < B_) { cnt_g[tid] = cnt[tid]; off_g[tid] = off[tid]; }
        for (int j = tid; j < B_ * MAXBB; j += 256) {
            int b = j >> 7, p = j & 127;
            att[j] = (p < cnt[b]) ? 1.0f : 0.0f;
        }
        return;
    }
    // weight/feature pack
    int pidx = bx - 2561;
    WDesc d = ws.d[pidx / 576];
    int idx = (pidx % 576) * 256 + tid;
    int Kc = d.K >> 3;
    int total = d.N * Kc;
    if (idx >= total) return;
    int n = idx / Kc, kc = idx - n * Kc;
    const float* s = d.src + (size_t)n * d.stride + kc * 8;
    float v[8];
    if (d.vec) {
        f32x4 v0 = *(const f32x4*)s, v1 = *(const f32x4*)(s + 4);
        #pragma unroll
        for (int j = 0; j < 4; ++j) { v[j] = v0[j]; v[4 + j] = v1[j]; }
    } else {
        #pragma unroll
        for (int j = 0; j < 8; ++j) v[j] = s[j];
    }
    bf16x8 hv, lv;
    #pragma unroll
    for (int j = 0; j < 8; ++j) {
        u16 h, l;
        split_bf(v[j], h, l); hv[j] = (short)h; lv[j] = (short)l;
    }
    size_t off = ((size_t)(n >> 4) * Kc + kc) * 128 + (n & 15) * 8;
    *(bf16x8*)(d.hi + off) = hv;
    *(bf16x8*)(d.lo + off) = lv;
}

// ============== device: mean final reduce + pack x -> tiled [kc=96][16][8] =
__device__ __forceinline__ void dev_mean_final(int b, int t, const float* __restrict__ part,
                                               u16* __restrict__ xph, u16* __restrict__ xpl,
                                               float* xm) {
    if (t < 192) {
        f32x4 s = {0.f, 0.f, 0.f, 0.f};
        #pragma unroll 4
        for (int c = 0; c < 64; ++c)
            s += *(const f32x4*)(part + ((size_t)(b * 64 + c)) * 768 + t * 4);
        s *= (1.0f / T_);
        *(f32x4*)(xm + t * 4) = s;
    }
    __syncthreads();
    if (t < 96) {
        const float* p = xm + t * 8;
        bf16x8 hv, lv;
        #pragma unroll
        for (int j = 0; j < 8; ++j) {
            u16 h, l;
            split_bf(p[j], h, l); hv[j] = (short)h; lv[j] = (short)l;
        }
        size_t off = ((size_t)t * 16 + b) * 8;
        *(bf16x8*)(xph + off) = hv;
        *(bf16x8*)(xpl + off) = lv;
    }
}

// ================= device: big MFMA GEMM slice (one-shot K, z=term) ========
// A,W tiled [t16][kc][16][8]. M=1024, N=768. 128x128 block, 4 waves 64x64.
// GATHER=1 (pw): k-steps 0..23 read gathered xt rows ([kc][16][8] by img),
// steps 24..47 read fm tiled (AKc=96).
template<int GATHER>
__device__ __forceinline__ void dev_mfma(const u16* __restrict__ Ahi, const u16* __restrict__ Alo,
                                         const u16* __restrict__ Whi, const u16* __restrict__ Wlo,
                                         const u16* __restrict__ Xth, const u16* __restrict__ Xtl,
                                         const int* __restrict__ bbx,
                                         float* __restrict__ P, int Kc,
                                         int bxn, int byn, int term, int tid) {
    int lane = tid & 63, w = tid >> 6;
    int wm = w >> 1, wn = w & 1;
    int mt0 = byn * 8 + wm * 4;
    int nt0 = bxn * 8 + wn * 4;
    int nk = Kc >> 2;

    const u16* W = (term == 1) ? Wlo : Whi;
    const u16* Wp = W + ((size_t)nt0 * Kc) * 128 + lane * 8;
    size_t wstr = (size_t)Kc * 128;

    const u16* Ab = (term == 2) ? Alo : Ahi;
    const u16* Xb = (term == 2) ? Xtl : Xth;
    int AKc = GATHER ? 96 : Kc;
    size_t aofs[4], xofs[4];
    #pragma unroll
    for (int i = 0; i < 4; ++i)
        aofs[i] = ((size_t)(mt0 + i) * AKc) * 128 + lane * 8;
    if (GATHER) {
        #pragma unroll
        for (int i = 0; i < 4; ++i) {
            int row = (mt0 + i) * 16 + (lane & 15);
            xofs[i] = (size_t)(lane >> 4) * 128 + (size_t)bbx[row * 5] * 8;
        }
    }

    auto LA = [&](int k, bf16x8 (&a)[4]) {
        if (GATHER && k < 24) {
            #pragma unroll
            for (int i = 0; i < 4; ++i)
                a[i] = *(const bf16x8*)(Xb + xofs[i] + (size_t)k * 512);
        } else {
            int kk = GATHER ? k - 24 : k;
            #pragma unroll
            for (int i = 0; i < 4; ++i)
                a[i] = *(const bf16x8*)(Ab + aofs[i] + (size_t)kk * 512);
        }
    };

    bf16x8 a[4], b[4];
    LA(0, a);
    #pragma unroll
    for (int i = 0; i < 4; ++i) b[i] = *(const bf16x8*)(Wp + i * wstr);

    f32x4 acc[16];
    #pragma unroll
    for (int i = 0; i < 16; ++i) acc[i] = (f32x4){0.f, 0.f, 0.f, 0.f};

    for (int k = 0; k < nk; ++k) {
        bf16x8 an[4], bn[4];
        if (k + 1 < nk) {
            LA(k + 1, an);
            #pragma unroll
            for (int i = 0; i < 4; ++i)
                bn[i] = *(const bf16x8*)(Wp + i * wstr + (size_t)(k + 1) * 512);
        }
        #pragma unroll
        for (int i = 0; i < 4; ++i)
            #pragma unroll
            for (int j = 0; j < 4; ++j)
                acc[i * 4 + j] = __builtin_amdgcn_mfma_f32_16x16x32_bf16(a[i], b[j], acc[i * 4 + j], 0, 0, 0);
        #pragma unroll
        for (int i = 0; i < 4; ++i) { a[i] = an[i]; b[i] = bn[i]; }
    }

    float* Pz = P + (size_t)term * (1024 * 768);
    int rb = (lane >> 4) * 4, cb = lane & 15;
    #pragma unroll
    for (int i = 0; i < 4; ++i)
        #pragma unroll
        for (int j = 0; j < 4; ++j) {
            int row = (mt0 + i) * 16 + rb;
            int col = (nt0 + j) * 16 + cb;
            float* p = Pz + (size_t)row * 768 + col;
            f32x4 v = acc[i * 4 + j];
            #pragma unroll
            for (int r = 0; r < 4; ++r) p[(size_t)r * 768] = v[r];
        }
}

// ============ device: big epilogue -> packed bf16 (3-slice reduce) =========
__device__ __forceinline__ void dev_epi_pack(int blk, int tid, int relu,
                                             const float* __restrict__ P,
                                             const float* __restrict__ bias,
                                             u16* __restrict__ dhi, u16* __restrict__ dlo,
                                             int KcDst, int kcOff) {
    int idx = blk * 256 + tid;                  // < 1024*96
    int m = idx / 96, kc = idx - m * 96;
    const float* p0 = P + (size_t)m * 768 + kc * 8;
    f32x4 s0 = *(const f32x4*)p0, s1 = *(const f32x4*)(p0 + 4);
    #pragma unroll
    for (int z = 1; z < 3; ++z) {
        const float* p = p0 + (size_t)z * (1024 * 768);
        s0 += *(const f32x4*)p; s1 += *(const f32x4*)(p + 4);
    }
    s0 += *(const f32x4*)(bias + kc * 8);
    s1 += *(const f32x4*)(bias + kc * 8 + 4);
    bf16x8 hv, lv;
    #pragma unroll
    for (int j = 0; j < 4; ++j) {
        float v0 = relu ? fmaxf(s0[j], 0.f) : s0[j];
        float v1 = relu ? fmaxf(s1[j], 0.f) : s1[j];
        u16 h, l;
        split_bf(v0, h, l); hv[j] = (short)h; lv[j] = (short)l;
        split_bf(v1, h, l); hv[4 + j] = (short)h; lv[4 + j] = (short)l;
    }
    size_t off = ((size_t)(m >> 4) * KcDst + kcOff + kc) * 128 + (m & 15) * 8;
    *(bf16x8*)(dhi + off) = hv;
    *(bf16x8*)(dlo + off) = lv;
}

// ======= device: big epilogue -> bias + scatter rows directly into vis =====
__device__ __forceinline__ void dev_epi_vis(int blk, int tid,
                                            const float* __restrict__ P,
                                            const float* __restrict__ bias,
                                            float* __restrict__ vis,
                                            const int* __restrict__ bbx,
                                            const int* __restrict__ off) {
    int idx = blk * 256 + tid;                  // < 1024*192
    int m = idx / 192, c4 = idx - m * 192;
    size_t o = (size_t)m * 768 + c4 * 4;
    f32x4 s = *(const f32x4*)(P + o);
    #pragma unroll
    for (int z = 1; z < 3; ++z) s += *(const f32x4*)(P + (size_t)z * (1024 * 768) + o);
    s += *(const f32x4*)(bias + c4 * 4);
    int b = bbx[m * 5];
    int pp = m - off[b];
    if (pp < MAXBB)
        *(f32x4*)&vis[((size_t)(b * MAXBB + pp)) * 768 + c4 * 4] = s;
}

// ================= device: small-M (M=16) GEMM slice =======================
// combined N=1536 [d|t]. bxn 0..5, z 0..11 (term*4+ks). Kc=96, slice 24.
__device__ __forceinline__ void dev_small(int bxn, int z, int tid,
                                          const u16* __restrict__ A0h, const u16* __restrict__ A0l,
                                          const u16* __restrict__ A1h, const u16* __restrict__ A1l,
                                          const u16* __restrict__ W0h, const u16* __restrict__ W0l,
                                          const u16* __restrict__ W1h, const u16* __restrict__ W1l,
                                          float* __restrict__ Ps) {
    int term = z >> 2, ks = z & 3;
    int lane = tid & 63, w = tid >> 6;
    int nt0 = bxn * 16 + w * 4;                  // global n-tile 0..95
    int path = nt0 >= 48;
    int ntp = nt0 - path * 48;
    const u16* Ah = path ? A1h : A0h;
    const u16* Al = path ? A1l : A0l;
    const u16* Wh = path ? W1h : W0h;
    const u16* Wl = path ? W1l : W0l;
    const u16* A = (term == 2) ? Al : Ah;
    const u16* W = (term == 1) ? Wl : Wh;
    int kc0 = ks * 24;

    const u16* Ap = A + (size_t)kc0 * 128 + lane * 8;
    const u16* Wp = W + ((size_t)ntp * 96 + kc0) * 128 + lane * 8;

    f32x4 acc[4];
    #pragma unroll
    for (int i = 0; i < 4; ++i) acc[i] = (f32x4){0.f, 0.f, 0.f, 0.f};

    #pragma unroll
    for (int k = 0; k < 6; ++k) {
        bf16x8 a = *(const bf16x8*)(Ap + (size_t)k * 512);
        bf16x8 b[4];
        #pragma unroll
        for (int j = 0; j < 4; ++j)
            b[j] = *(const bf16x8*)(Wp + (size_t)j * 96 * 128 + (size_t)k * 512);
        #pragma unroll
        for (int j = 0; j < 4; ++j)
            acc[j] = __builtin_amdgcn_mfma_f32_16x16x32_bf16(a, b[j], acc[j], 0, 0, 0);
    }

    float* Pz = Ps + (size_t)z * (16 * 1536);
    int rb = (lane >> 4) * 4, cb = lane & 15;
    #pragma unroll
    for (int j = 0; j < 4; ++j) {
        int col = (nt0 + j) * 16 + cb;
        float* p = Pz + (size_t)rb * 1536 + col;
        f32x4 v = acc[j];
        #pragma unroll
        for (int r = 0; r < 4; ++r) p[(size_t)r * 1536] = v[r];
    }
}

// ============ device: small epilogue 1 (relu -> xc packed) =================
__device__ __forceinline__ void dev_sepi1(int blk, int tid,
                                          const float* __restrict__ Ps,
                                          const float* __restrict__ d1b, const float* __restrict__ t1b,
                                          u16* __restrict__ xh, u16* __restrict__ xl) {
    int idx = blk * 256 + tid;                   // < 16*192
    int r = idx / 192, cc = idx - r * 192;
    size_t base = (size_t)r * 1536 + cc * 8;
    f32x4 s0 = {0,0,0,0}, s1 = {0,0,0,0};
    for (int z = 0; z < 12; ++z) {
        const float* p = Ps + (size_t)z * (16 * 1536) + base;
        s0 += *(const f32x4*)p; s1 += *(const f32x4*)(p + 4);
    }
    int path = cc >= 96;
    int ccp = cc - path * 96;
    const float* bias = (path ? t1b : d1b) + ccp * 8;
    s0 += *(const f32x4*)bias;
    s1 += *(const f32x4*)(bias + 4);
    bf16x8 hv, lv;
    #pragma unroll
    for (int j = 0; j < 4; ++j) {
        u16 h, l;
        split_bf(fmaxf(s0[j], 0.f), h, l); hv[j] = (short)h; lv[j] = (short)l;
        split_bf(fmaxf(s1[j], 0.f), h, l); hv[4 + j] = (short)h; lv[4 + j] = (short)l;
    }
    size_t off = (size_t)path * 12288 + (size_t)ccp * 128 + r * 8;
    *(bf16x8*)(xh + off) = hv;
    *(bf16x8*)(xl + off) = lv;
}

// ===== device: small epilogue 2 (d -> retx fp32, t -> xt packed) ===========
__device__ __forceinline__ void dev_sepi2(int blk, int tid,
                                          const float* __restrict__ Ps,
                                          const float* __restrict__ d2b, const float* __restrict__ t2b,
                                          float* __restrict__ retx,
                                          u16* __restrict__ xth, u16* __restrict__ xtl) {
    int idx = blk * 256 + tid;                   // < 16*192
    int r = idx / 192, cc = idx - r * 192;
    size_t base = (size_t)r * 1536 + cc * 8;
    f32x4 s0 = {0,0,0,0}, s1 = {0,0,0,0};
    for (int z = 0; z < 12; ++z) {
        const float* p = Ps + (size_t)z * (16 * 1536) + base;
        s0 += *(const f32x4*)p; s1 += *(const f32x4*)(p + 4);
    }
    int path = cc >= 96;
    int ccp = cc - path * 96;
    const float* bias = (path ? t2b : d2b) + ccp * 8;
    s0 += *(const f32x4*)bias;
    s1 += *(const f32x4*)(bias + 4);
    if (!path) {
        float* o = retx + (size_t)r * 768 + ccp * 8;
        *(f32x4*)o = s0;
        *(f32x4*)(o + 4) = s1;
    } else {
        bf16x8 hv, lv;
        #pragma unroll
        for (int j = 0; j < 4; ++j) {
            u16 h, l;
            split_bf(s0[j], h, l); hv[j] = (short)h; lv[j] = (short)l;
            split_bf(s1[j], h, l); hv[4 + j] = (short)h; lv[4 + j] = (short)l;
        }
        size_t off = (size_t)ccp * 128 + r * 8;
        *(bf16x8*)(xth + off) = hv;
        *(bf16x8*)(xtl + off) = lv;
    }
}

// ================= cooperative chain kernel (phases L2..L8) ================
struct ChainArgs {
    const float* part;
    float* P; float* Ps;
    u16 *xph, *xpl, *xch, *xcl, *xth, *xtl;
    const u16 *feah, *feal;
    u16 *fm1h, *fm1l, *fmh, *fml;
    const u16 *d1wh, *d1wl, *t1wh, *t1wl, *d2wh, *d2wl, *t2wh, *t2wl;
    const u16 *m1wh, *m1wl, *m2wh, *m2wl, *pwh, *pwl;
    const float *d1b, *t1b, *d2b, *t2b, *m1b, *m2b, *pb;
    float* retx; float* vis;
    const int* bbx; const int* off;
};

__global__ __launch_bounds__(256) void k_chain(ChainArgs A) {
    cg::grid_group grid = cg::this_grid();
    int bx = blockIdx.x, tid = threadIdx.x;
    __shared__ float xm[768];

    // P1: mean_final (0..15) || m1 GEMM (16..159, Kc=32 one-shot)
    if (bx < 16) {
        dev_mean_final(bx, tid, A.part, A.xph, A.xpl, xm);
    } else if (bx < 160) {
        int i = bx - 16;
        dev_mfma<0>(A.feah, A.feal, A.m1wh, A.m1wl, nullptr, nullptr, nullptr,
                    A.P, 32, i % 6, (i / 6) % 8, i / 48, tid);
    }
    grid.sync();

    // P2: small1 (0..71) || m1 epilogue -> fm1 packed (384 strided)
    if (bx < 72)
        dev_small(bx % 6, bx / 6, tid, A.xph, A.xpl, A.xph, A.xpl,
                  A.d1wh, A.d1wl, A.t1wh, A.t1wl, A.Ps);
    for (int u = bx; u < 384; u += 256)
        dev_epi_pack(u, tid, 1, A.P, A.m1b, A.fm1h, A.fm1l, 96, 0);
    grid.sync();

    // P3: sepi1 (0..11) || m2 GEMM (16..159, Kc=96 one-shot)
    if (bx < 12) {
        dev_sepi1(bx, tid, A.Ps, A.d1b, A.t1b, A.xch, A.xcl);
    } else if (bx >= 16 && bx < 160) {
        int i = bx - 16;
        dev_mfma<0>(A.fm1h, A.fm1l, A.m2wh, A.m2wl, nullptr, nullptr, nullptr,
                    A.P, 96, i % 6, (i / 6) % 8, i / 48, tid);
    }
    grid.sync();

    // P4: small2 (0..71) || m2 epilogue -> fm packed (384 strided)
    if (bx < 72)
        dev_small(bx % 6, bx / 6, tid, A.xch, A.xcl, A.xch + 12288, A.xcl + 12288,
                  A.d2wh, A.d2wl, A.t2wh, A.t2wl, A.Ps);
    for (int u = bx; u < 384; u += 256)
        dev_epi_pack(u, tid, 0, A.P, A.m2b, A.fmh, A.fml, 96, 0);
    grid.sync();

    // P5: sepi2 (0..11) -> retx | xt
    if (bx < 12)
        dev_sepi2(bx, tid, A.Ps, A.d2b, A.t2b, A.retx, A.xth, A.xtl);
    grid.sync();

    // P6: pw GEMM (16..159, Kc=192 one-shot, xt-gather first half)
    if (bx >= 16 && bx < 160) {
        int i = bx - 16;
        dev_mfma<1>(A.fmh, A.fml, A.pwh, A.pwl, A.xth, A.xtl, A.bbx,
                    A.P, 192, i % 6, (i / 6) % 8, i / 48, tid);
    }
    grid.sync();

    // P7: bias + scatter into vis (768 strided)
    for (int u = bx; u < 768; u += 256)
        dev_epi_vis(u, tid, A.P, A.pb, A.vis, A.bbx, A.off);
}

extern "C" void kernel_launch(void* const* d_in, const int* in_sizes, int n_in,
                              void* d_out, int out_size, void* d_ws, size_t ws_size,
                              hipStream_t stream) {
    const float* inputs   = (const float*)d_in[0];
    const int*   bboxes   = (const int*)d_in[1];
    const float* features = (const float*)d_in[2];
    const float* t1w = (const float*)d_in[3];
    const float* t1b = (const float*)d_in[4];
    const float* t2w = (const float*)d_in[5];
    const float* t2b = (const float*)d_in[6];
    const float* d1w = (const float*)d_in[7];
    const float* d1b = (const float*)d_in[8];
    const float* d2w = (const float*)d_in[9];
    const float* d2b = (const float*)d_in[10];
    const float* m1w = (const float*)d_in[11];
    const float* m1b = (const float*)d_in[12];
    const float* m2w = (const float*)d_in[13];
    const float* m2b = (const float*)d_in[14];
    const float* pw  = (const float*)d_in[15];
    const float* pb  = (const float*)d_in[16];

    float* out  = (float*)d_out;
    float* vis  = out;                       // 16*128*768
    float* att  = out + 1572864;             // 2048
    float* retx = out + 1574912;             // 12288

    // ---- workspace layout (floats) ----
    float* wsf  = (float*)d_ws;
    float* part = wsf;                        // 786432
    float* P    = wsf + 786432;               // 3 * 786432
    float* Ps   = P + 3 * 786432;             // 12 * 24576 = 294912
    int*   cnt  = (int*)(Ps + 294912);        // 16
    int*   off  = cnt + 16;                   // 16 (pad to 48)
    u16*   sb   = (u16*)(off + 48);           // bf16 region (16B aligned)

    u16* t1wh = sb;              u16* t1wl = t1wh + 589824;
    u16* t2wh = t1wl + 589824;   u16* t2wl = t2wh + 589824;
    u16* d1wh = t2wl + 589824;   u16* d1wl = d1wh + 589824;
    u16* d2wh = d1wl + 589824;   u16* d2wl = d2wh + 589824;
    u16* m1wh = d2wl + 589824;   u16* m1wl = m1wh + 196608;
    u16* m2wh = m1wl + 196608;   u16* m2wl = m2wh + 589824;
    u16* pwh  = m2wl + 589824;   u16* pwl  = pwh + 1179648;
    u16* feah = pwl + 1179648;   u16* feal = feah + 262144;
    u16* fm1h = feal + 262144;   u16* fm1l = fm1h + 786432;
    u16* fmh  = fm1l + 786432;   u16* fml  = fmh + 786432;
    u16* xph  = fml + 786432;    u16* xpl  = xph + 12288;
    u16* xch  = xpl + 12288;     u16* xcl  = xch + 24576;
    u16* xth  = xcl + 24576;     u16* xtl  = xth + 12288;

    // L1: mean_partial || meta+viszero || pack (weights + features)
    WPack8 wp;
    wp.d[0] = {t1w, t1wh, t1wl, 768, 768, 768, 1};
    wp.d[1] = {t2w, t2wh, t2wl, 768, 768, 768, 1};
    wp.d[2] = {d1w, d1wh, d1wl, 768, 768, 768, 1};
    wp.d[3] = {d2w, d2wh, d2wl, 768, 768, 768, 1};
    wp.d[4] = {m1w, m1wh, m1wl, 768, 256, 256, 1};
    wp.d[5] = {m2w, m2wh, m2wl, 768, 768, 768, 1};
    wp.d[6] = {pw,  pwh,  pwl,  768, 1536, 1536, 1};
    wp.d[7] = {features + 1, feah, feal, 1024, 256, 257, 0};
    k_front<<<7169, 256, 0, stream>>>(wp, (const float4*)inputs, (float4*)part,
                                      bboxes, cnt, off, att, (f32x4*)vis);

    // L2: cooperative chain (6 grid syncs, 8 phases)
    ChainArgs ca;
    ca.part = part; ca.P = P; ca.Ps = Ps;
    ca.xph = xph; ca.xpl = xpl; ca.xch = xch; ca.xcl = xcl; ca.xth = xth; ca.xtl = xtl;
    ca.feah = feah; ca.feal = feal;
    ca.fm1h = fm1h; ca.fm1l = fm1l; ca.fmh = fmh; ca.fml = fml;
    ca.d1wh = d1wh; ca.d1wl = d1wl; ca.t1wh = t1wh; ca.t1wl = t1wl;
    ca.d2wh = d2wh; ca.d2wl = d2wl; ca.t2wh = t2wh; ca.t2wl = t2wl;
    ca.m1wh = m1wh; ca.m1wl = m1wl; ca.m2wh = m2wh; ca.m2wl = m2wl;
    ca.pwh = pwh; ca.pwl = pwl;
    ca.d1b = d1b; ca.t1b = t1b; ca.d2b = d2b; ca.t2b = t2b;
    ca.m1b = m1b; ca.m2b = m2b; ca.pb = pb;
    ca.retx = retx; ca.vis = vis;
    ca.bbx = bboxes; ca.off = off;

    void* args[] = { &ca };
    hipLaunchCooperativeKernel(k_chain, dim3(256), dim3(256), args, 0, stream);
}

// Round 5
// 407.928 us; speedup vs baseline: 1.4894x; 1.4894x over previous
//
#include <hip/hip_runtime.h>

#define B_ 16
#define T_ 4096
#define D_ 768
#define NBOX 1024
#define MAXBB 128
#define DDETR 256

typedef unsigned short u16;
typedef short bf16x8 __attribute__((ext_vector_type(8)));
typedef float f32x4 __attribute__((ext_vector_type(4)));

// round-to-nearest-even fp32 -> bf16 split: f ~= hi + lo (both bf16)
__device__ __forceinline__ void split_bf(float f, u16& h, u16& l) {
    unsigned u = __builtin_bit_cast(unsigned, f);
    unsigned r = u + 0x7fffu + ((u >> 16) & 1u);
    u16 hb = (u16)(r >> 16);
    float hf = __builtin_bit_cast(float, (unsigned)hb << 16);
    float lf = f - hf;
    unsigned ul = __builtin_bit_cast(unsigned, lf);
    unsigned rl = ul + 0x7fffu + ((ul >> 16) & 1u);
    h = hb; l = (u16)(rl >> 16);
}

struct WDesc { const float* src; u16* hi; u16* lo; int N; int K; int stride; int vec; };
struct WPack8 { WDesc d[8]; };

// ================= front kernel: mean_partial || meta+viszero || pack ======
__global__ __launch_bounds__(256) void k_front(WPack8 ws,
                                               const float4* __restrict__ in4,
                                               float4* __restrict__ part4,
                                               const int* __restrict__ bboxes,
                                               int* __restrict__ cnt_g, int* __restrict__ off_g,
                                               float* __restrict__ att, f32x4* __restrict__ vis4) {
    int bx = blockIdx.x;
    int tid = threadIdx.x;
    if (bx < 1024) {
        // mean partial: block (b, c), threads 0..191 active
        if (tid >= 192) return;
        int b = bx >> 6, c = bx & 63;
        const float4* base = in4 + (size_t)b * (T_ * D_ / 4) + (size_t)c * (64 * D_ / 4);
        float4 s = {0.f, 0.f, 0.f, 0.f};
        #pragma unroll 4
        for (int r = 0; r < 64; ++r) {
            float4 v = base[(size_t)r * 192 + tid];
            s.x += v.x; s.y += v.y; s.z += v.z; s.w += v.w;
        }
        part4[(size_t)bx * 192 + tid] = s;
        return;
    }
    if (bx < 2561) {
        int mb = bx - 1024;
        if (mb > 0) {
            int idx = (mb - 1) * 256 + tid;    // < 393216
            vis4[idx] = (f32x4){0.f, 0.f, 0.f, 0.f};
            return;
        }
        __shared__ int cnt[B_];
        __shared__ int off[B_];
        if (tid < B_) cnt[tid] = 0;
        __syncthreads();
        for (int i = tid; i < NBOX; i += 256) atomicAdd(&cnt[bboxes[i * 5]], 1);
        __syncthreads();
        if (tid == 0) {
            int acc = 0;
            for (int b = 0; b < B_; ++b) { off[b] = acc; acc += cnt[b]; }
        }
        __syncthreads();
        if (tid < B_) { cnt_g[tid] = cnt[tid]; off_g[tid] = off[tid]; }
        for (int j = tid; j < B_ * MAXBB; j += 256) {
            int b = j >> 7, p = j & 127;
            att[j] = (p < cnt[b]) ? 1.0f : 0.0f;
        }
        return;
    }
    // weight/feature pack
    int pidx = bx - 2561;
    WDesc d = ws.d[pidx / 576];
    int idx = (pidx % 576) * 256 + tid;
    int Kc = d.K >> 3;
    int total = d.N * Kc;
    if (idx >= total) return;
    int n = idx / Kc, kc = idx - n * Kc;
    const float* s = d.src + (size_t)n * d.stride + kc * 8;
    float v[8];
    if (d.vec) {
        f32x4 v0 = *(const f32x4*)s, v1 = *(const f32x4*)(s + 4);
        #pragma unroll
        for (int j = 0; j < 4; ++j) { v[j] = v0[j]; v[4 + j] = v1[j]; }
    } else {
        #pragma unroll
        for (int j = 0; j < 8; ++j) v[j] = s[j];
    }
    bf16x8 hv, lv;
    #pragma unroll
    for (int j = 0; j < 8; ++j) {
        u16 h, l;
        split_bf(v[j], h, l); hv[j] = (short)h; lv[j] = (short)l;
    }
    size_t off = ((size_t)(n >> 4) * Kc + kc) * 128 + (n & 15) * 8;
    *(bf16x8*)(d.hi + off) = hv;
    *(bf16x8*)(d.lo + off) = lv;
}

// ============== mean final reduce + pack x -> tiled [kc=96][16][8] =========
__global__ __launch_bounds__(256) void k_mean_final(const float* __restrict__ part,
                                                    u16* __restrict__ xph, u16* __restrict__ xpl) {
    __shared__ float xm[768];
    int b = blockIdx.x;          // 0..15
    int t = threadIdx.x;
    if (t < 192) {
        f32x4 s = {0.f, 0.f, 0.f, 0.f};
        #pragma unroll 4
        for (int c = 0; c < 64; ++c)
            s += *(const f32x4*)(part + ((size_t)(b * 64 + c)) * 768 + t * 4);
        s *= (1.0f / T_);
        *(f32x4*)(xm + t * 4) = s;
    }
    __syncthreads();
    if (t < 96) {
        const float* p = xm + t * 8;
        bf16x8 hv, lv;
        #pragma unroll
        for (int j = 0; j < 8; ++j) {
            u16 h, l;
            split_bf(p[j], h, l); hv[j] = (short)h; lv[j] = (short)l;
        }
        size_t off = ((size_t)t * 16 + b) * 8;
        *(bf16x8*)(xph + off) = hv;
        *(bf16x8*)(xpl + off) = lv;
    }
}

// ====== device: big MFMA GEMM slice, 512-thr block (8 waves of 64x32) ======
// A,W tiled [t16][kc][16][8]. M=1024, N=768. 128x128 block tile, one-shot K.
// GATHER=1 (pw): k-steps 0..23 read gathered xt rows ([kc][16][8] by img),
// steps 24..47 read fm tiled (AKc=96).
template<int GATHER>
__device__ __forceinline__ void dev_mfma512(const u16* __restrict__ Ahi, const u16* __restrict__ Alo,
                                            const u16* __restrict__ Whi, const u16* __restrict__ Wlo,
                                            const u16* __restrict__ Xth, const u16* __restrict__ Xtl,
                                            const int* __restrict__ bbx,
                                            float* __restrict__ P, int Kc,
                                            int bxn, int byn, int term, int tid) {
    int lane = tid & 63, w = tid >> 6;
    int wm = w >> 2, wn = w & 3;
    int mt0 = byn * 8 + wm * 4;         // 4 row-tiles (64 rows)
    int nt0 = bxn * 8 + wn * 2;         // 2 col-tiles (32 cols)
    int nk = Kc >> 2;

    const u16* W = (term == 1) ? Wlo : Whi;
    const u16* Wp = W + ((size_t)nt0 * Kc) * 128 + lane * 8;
    size_t wstr = (size_t)Kc * 128;

    const u16* Ab = (term == 2) ? Alo : Ahi;
    const u16* Xb = (term == 2) ? Xtl : Xth;
    int AKc = GATHER ? 96 : Kc;
    size_t aofs[4], xofs[4];
    #pragma unroll
    for (int i = 0; i < 4; ++i)
        aofs[i] = ((size_t)(mt0 + i) * AKc) * 128 + lane * 8;
    if (GATHER) {
        #pragma unroll
        for (int i = 0; i < 4; ++i) {
            int row = (mt0 + i) * 16 + (lane & 15);
            xofs[i] = (size_t)(lane >> 4) * 128 + (size_t)bbx[row * 5] * 8;
        }
    }

    auto LA = [&](int k, bf16x8 (&a)[4]) {
        if (GATHER && k < 24) {
            #pragma unroll
            for (int i = 0; i < 4; ++i)
                a[i] = *(const bf16x8*)(Xb + xofs[i] + (size_t)k * 512);
        } else {
            int kk = GATHER ? k - 24 : k;
            #pragma unroll
            for (int i = 0; i < 4; ++i)
                a[i] = *(const bf16x8*)(Ab + aofs[i] + (size_t)kk * 512);
        }
    };

    bf16x8 a[4], b[2];
    LA(0, a);
    #pragma unroll
    for (int j = 0; j < 2; ++j) b[j] = *(const bf16x8*)(Wp + j * wstr);

    f32x4 acc[8];
    #pragma unroll
    for (int i = 0; i < 8; ++i) acc[i] = (f32x4){0.f, 0.f, 0.f, 0.f};

    for (int k = 0; k < nk; ++k) {
        bf16x8 an[4], bn[2];
        if (k + 1 < nk) {
            LA(k + 1, an);
            #pragma unroll
            for (int j = 0; j < 2; ++j)
                bn[j] = *(const bf16x8*)(Wp + j * wstr + (size_t)(k + 1) * 512);
        }
        #pragma unroll
        for (int i = 0; i < 4; ++i)
            #pragma unroll
            for (int j = 0; j < 2; ++j)
                acc[i * 2 + j] = __builtin_amdgcn_mfma_f32_16x16x32_bf16(a[i], b[j], acc[i * 2 + j], 0, 0, 0);
        #pragma unroll
        for (int i = 0; i < 4; ++i) a[i] = an[i];
        #pragma unroll
        for (int j = 0; j < 2; ++j) b[j] = bn[j];
    }

    float* Pz = P + (size_t)term * (1024 * 768);
    int rb = (lane >> 4) * 4, cb = lane & 15;
    #pragma unroll
    for (int i = 0; i < 4; ++i)
        #pragma unroll
        for (int j = 0; j < 2; ++j) {
            int row = (mt0 + i) * 16 + rb;
            int col = (nt0 + j) * 16 + cb;
            float* p = Pz + (size_t)row * 768 + col;
            f32x4 v = acc[i * 2 + j];
            #pragma unroll
            for (int r = 0; r < 4; ++r) p[(size_t)r * 768] = v[r];
        }
}

// ============ device: big epilogue -> packed bf16 (3-slice reduce) =========
__device__ __forceinline__ void dev_epi_pack(int blk, int tid, int relu,
                                             const float* __restrict__ P,
                                             const float* __restrict__ bias,
                                             u16* __restrict__ dhi, u16* __restrict__ dlo,
                                             int KcDst, int kcOff) {
    int idx = blk * 256 + tid;                  // < 1024*96
    int m = idx / 96, kc = idx - m * 96;
    const float* p0 = P + (size_t)m * 768 + kc * 8;
    f32x4 s0 = *(const f32x4*)p0, s1 = *(const f32x4*)(p0 + 4);
    #pragma unroll
    for (int z = 1; z < 3; ++z) {
        const float* p = p0 + (size_t)z * (1024 * 768);
        s0 += *(const f32x4*)p; s1 += *(const f32x4*)(p + 4);
    }
    s0 += *(const f32x4*)(bias + kc * 8);
    s1 += *(const f32x4*)(bias + kc * 8 + 4);
    bf16x8 hv, lv;
    #pragma unroll
    for (int j = 0; j < 4; ++j) {
        float v0 = relu ? fmaxf(s0[j], 0.f) : s0[j];
        float v1 = relu ? fmaxf(s1[j], 0.f) : s1[j];
        u16 h, l;
        split_bf(v0, h, l); hv[j] = (short)h; lv[j] = (short)l;
        split_bf(v1, h, l); hv[4 + j] = (short)h; lv[4 + j] = (short)l;
    }
    size_t off = ((size_t)(m >> 4) * KcDst + kcOff + kc) * 128 + (m & 15) * 8;
    *(bf16x8*)(dhi + off) = hv;
    *(bf16x8*)(dlo + off) = lv;
}

// ============ big epilogue -> bias + scatter rows directly into vis ========
__global__ __launch_bounds__(256) void k_epi_vis(const float* __restrict__ P,
                                                 const float* __restrict__ bias,
                                                 float* __restrict__ vis,
                                                 const int* __restrict__ bbx,
                                                 const int* __restrict__ off) {
    int idx = blockIdx.x * 256 + threadIdx.x;   // < 1024*192
    int m = idx / 192, c4 = idx - m * 192;
    size_t o = (size_t)m * 768 + c4 * 4;
    f32x4 s = *(const f32x4*)(P + o);
    #pragma unroll
    for (int z = 1; z < 3; ++z) s += *(const f32x4*)(P + (size_t)z * (1024 * 768) + o);
    s += *(const f32x4*)(bias + c4 * 4);
    int b = bbx[m * 5];
    int pp = m - off[b];
    if (pp < MAXBB)
        *(f32x4*)&vis[((size_t)(b * MAXBB + pp)) * 768 + c4 * 4] = s;
}

// ================= device: small-M (M=16) GEMM slice =======================
// combined N=1536 [d|t]. bxn 0..5, z 0..11 (term*4+ks), w4 0..3. Kc=96.
__device__ __forceinline__ void dev_small(int bxn, int z, int lane, int w4,
                                          const u16* __restrict__ A0h, const u16* __restrict__ A0l,
                                          const u16* __restrict__ A1h, const u16* __restrict__ A1l,
                                          const u16* __restrict__ W0h, const u16* __restrict__ W0l,
                                          const u16* __restrict__ W1h, const u16* __restrict__ W1l,
                                          float* __restrict__ Ps) {
    int term = z >> 2, ks = z & 3;
    int nt0 = bxn * 16 + w4 * 4;                 // global n-tile 0..95
    int path = nt0 >= 48;
    int ntp = nt0 - path * 48;
    const u16* Ah = path ? A1h : A0h;
    const u16* Al = path ? A1l : A0l;
    const u16* Wh = path ? W1h : W0h;
    const u16* Wl = path ? W1l : W0l;
    const u16* A = (term == 2) ? Al : Ah;
    const u16* W = (term == 1) ? Wl : Wh;
    int kc0 = ks * 24;

    const u16* Ap = A + (size_t)kc0 * 128 + lane * 8;
    const u16* Wp = W + ((size_t)ntp * 96 + kc0) * 128 + lane * 8;

    f32x4 acc[4];
    #pragma unroll
    for (int i = 0; i < 4; ++i) acc[i] = (f32x4){0.f, 0.f, 0.f, 0.f};

    #pragma unroll
    for (int k = 0; k < 6; ++k) {
        bf16x8 a = *(const bf16x8*)(Ap + (size_t)k * 512);
        bf16x8 b[4];
        #pragma unroll
        for (int j = 0; j < 4; ++j)
            b[j] = *(const bf16x8*)(Wp + (size_t)j * 96 * 128 + (size_t)k * 512);
        #pragma unroll
        for (int j = 0; j < 4; ++j)
            acc[j] = __builtin_amdgcn_mfma_f32_16x16x32_bf16(a, b[j], acc[j], 0, 0, 0);
    }

    float* Pz = Ps + (size_t)z * (16 * 1536);
    int rb = (lane >> 4) * 4, cb = lane & 15;
    #pragma unroll
    for (int j = 0; j < 4; ++j) {
        int col = (nt0 + j) * 16 + cb;
        float* p = Pz + (size_t)rb * 1536 + col;
        f32x4 v = acc[j];
        #pragma unroll
        for (int r = 0; r < 4; ++r) p[(size_t)r * 1536] = v[r];
    }
}

// ============ device: small epilogue 1 (relu -> xc packed) =================
__device__ __forceinline__ void dev_sepi1(int blk, int tid,
                                          const float* __restrict__ Ps,
                                          const float* __restrict__ d1b, const float* __restrict__ t1b,
                                          u16* __restrict__ xh, u16* __restrict__ xl) {
    int idx = blk * 256 + tid;                   // < 16*192
    int r = idx / 192, cc = idx - r * 192;
    size_t base = (size_t)r * 1536 + cc * 8;
    f32x4 s0 = {0,0,0,0}, s1 = {0,0,0,0};
    for (int z = 0; z < 12; ++z) {
        const float* p = Ps + (size_t)z * (16 * 1536) + base;
        s0 += *(const f32x4*)p; s1 += *(const f32x4*)(p + 4);
    }
    int path = cc >= 96;
    int ccp = cc - path * 96;
    const float* bias = (path ? t1b : d1b) + ccp * 8;
    s0 += *(const f32x4*)bias;
    s1 += *(const f32x4*)(bias + 4);
    bf16x8 hv, lv;
    #pragma unroll
    for (int j = 0; j < 4; ++j) {
        u16 h, l;
        split_bf(fmaxf(s0[j], 0.f), h, l); hv[j] = (short)h; lv[j] = (short)l;
        split_bf(fmaxf(s1[j], 0.f), h, l); hv[4 + j] = (short)h; lv[4 + j] = (short)l;
    }
    size_t off = (size_t)path * 12288 + (size_t)ccp * 128 + r * 8;
    *(bf16x8*)(xh + off) = hv;
    *(bf16x8*)(xl + off) = lv;
}

// ===== device: small epilogue 2 (d -> retx fp32, t -> xt packed) ===========
__device__ __forceinline__ void dev_sepi2(int blk, int tid,
                                          const float* __restrict__ Ps,
                                          const float* __restrict__ d2b, const float* __restrict__ t2b,
                                          float* __restrict__ retx,
                                          u16* __restrict__ xth, u16* __restrict__ xtl) {
    int idx = blk * 256 + tid;                   // < 16*192
    int r = idx / 192, cc = idx - r * 192;
    size_t base = (size_t)r * 1536 + cc * 8;
    f32x4 s0 = {0,0,0,0}, s1 = {0,0,0,0};
    for (int z = 0; z < 12; ++z) {
        const float* p = Ps + (size_t)z * (16 * 1536) + base;
        s0 += *(const f32x4*)p; s1 += *(const f32x4*)(p + 4);
    }
    int path = cc >= 96;
    int ccp = cc - path * 96;
    const float* bias = (path ? t2b : d2b) + ccp * 8;
    s0 += *(const f32x4*)bias;
    s1 += *(const f32x4*)(bias + 4);
    if (!path) {
        float* o = retx + (size_t)r * 768 + ccp * 8;
        *(f32x4*)o = s0;
        *(f32x4*)(o + 4) = s1;
    } else {
        bf16x8 hv, lv;
        #pragma unroll
        for (int j = 0; j < 4; ++j) {
            u16 h, l;
            split_bf(s0[j], h, l); hv[j] = (short)h; lv[j] = (short)l;
            split_bf(s1[j], h, l); hv[4 + j] = (short)h; lv[4 + j] = (short)l;
        }
        size_t off = (size_t)ccp * 128 + r * 8;
        *(bf16x8*)(xth + off) = hv;
        *(bf16x8*)(xtl + off) = lv;
    }
}

// ================= phase kernels (independent work merged) =================
// phase A (512t): small1 pairs (36 blocks) || m1-GEMM512 (144 blocks, Kc=32)
__global__ __launch_bounds__(512) void k_phaseA(const u16* xph, const u16* xpl,
                                                const u16* d1wh, const u16* d1wl,
                                                const u16* t1wh, const u16* t1wl,
                                                float* Ps,
                                                const u16* feah, const u16* feal,
                                                const u16* m1wh, const u16* m1wl,
                                                float* P) {
    int bx = blockIdx.x, tid = threadIdx.x;
    int lane = tid & 63, w = tid >> 6;
    if (bx < 36) {
        dev_small(bx % 6, (bx / 6) * 2 + (w >> 2), lane, w & 3,
                  xph, xpl, xph, xpl, d1wh, d1wl, t1wh, t1wl, Ps);
    } else {
        int i = bx - 36;
        dev_mfma512<0>(feah, feal, m1wh, m1wl, nullptr, nullptr, nullptr,
                       P, 32, i % 6, (i / 6) % 8, i / 48, tid);
    }
}

// phase B (256t): sepi1 (12) || m1 epilogue -> fm1 packed (384)
__global__ __launch_bounds__(256) void k_phaseB(const float* Ps,
                                                const float* d1b, const float* t1b,
                                                u16* xch, u16* xcl,
                                                const float* P, const float* m1b,
                                                u16* fm1h, u16* fm1l) {
    int bx = blockIdx.x, tid = threadIdx.x;
    if (bx < 12) dev_sepi1(bx, tid, Ps, d1b, t1b, xch, xcl);
    else dev_epi_pack(bx - 12, tid, 1, P, m1b, fm1h, fm1l, 96, 0);
}

// phase C (512t): small2 pairs (36) || m2-GEMM512 (144, Kc=96)
__global__ __launch_bounds__(512) void k_phaseC(const u16* xch, const u16* xcl,
                                                const u16* d2wh, const u16* d2wl,
                                                const u16* t2wh, const u16* t2wl,
                                                float* Ps,
                                                const u16* fm1h, const u16* fm1l,
                                                const u16* m2wh, const u16* m2wl,
                                                float* P) {
    int bx = blockIdx.x, tid = threadIdx.x;
    int lane = tid & 63, w = tid >> 6;
    if (bx < 36) {
        dev_small(bx % 6, (bx / 6) * 2 + (w >> 2), lane, w & 3,
                  xch, xcl, xch + 12288, xcl + 12288, d2wh, d2wl, t2wh, t2wl, Ps);
    } else {
        int i = bx - 36;
        dev_mfma512<0>(fm1h, fm1l, m2wh, m2wl, nullptr, nullptr, nullptr,
                       P, 96, i % 6, (i / 6) % 8, i / 48, tid);
    }
}

// phase D (256t): sepi2 (12) || m2 epilogue -> fm packed (384)
__global__ __launch_bounds__(256) void k_phaseD(const float* Ps,
                                                const float* d2b, const float* t2b,
                                                float* retx, u16* xth, u16* xtl,
                                                const float* P, const float* m2b,
                                                u16* fmh, u16* fml) {
    int bx = blockIdx.x, tid = threadIdx.x;
    if (bx < 12) dev_sepi2(bx, tid, Ps, d2b, t2b, retx, xth, xtl);
    else dev_epi_pack(bx - 12, tid, 0, P, m2b, fmh, fml, 96, 0);
}

// pw GEMM (512t): one-shot K=192 per term, xt-gather for first half
__global__ __launch_bounds__(512) void k_pw(const u16* fmh, const u16* fml,
                                            const u16* pwh, const u16* pwl,
                                            const u16* xth, const u16* xtl,
                                            const int* bbx, float* P) {
    int i = blockIdx.x, tid = threadIdx.x;
    dev_mfma512<1>(fmh, fml, pwh, pwl, xth, xtl, bbx,
                   P, 192, i % 6, (i / 6) % 8, i / 48, tid);
}

extern "C" void kernel_launch(void* const* d_in, const int* in_sizes, int n_in,
                              void* d_out, int out_size, void* d_ws, size_t ws_size,
                              hipStream_t stream) {
    const float* inputs   = (const float*)d_in[0];
    const int*   bboxes   = (const int*)d_in[1];
    const float* features = (const float*)d_in[2];
    const float* t1w = (const float*)d_in[3];
    const float* t1b = (const float*)d_in[4];
    const float* t2w = (const float*)d_in[5];
    const float* t2b = (const float*)d_in[6];
    const float* d1w = (const float*)d_in[7];
    const float* d1b = (const float*)d_in[8];
    const float* d2w = (const float*)d_in[9];
    const float* d2b = (const float*)d_in[10];
    const float* m1w = (const float*)d_in[11];
    const float* m1b = (const float*)d_in[12];
    const float* m2w = (const float*)d_in[13];
    const float* m2b = (const float*)d_in[14];
    const float* pw  = (const float*)d_in[15];
    const float* pb  = (const float*)d_in[16];

    float* out  = (float*)d_out;
    float* vis  = out;                       // 16*128*768
    float* att  = out + 1572864;             // 2048
    float* retx = out + 1574912;             // 12288

    // ---- workspace layout (floats) ----
    float* wsf  = (float*)d_ws;
    float* part = wsf;                        // 786432
    float* P    = wsf + 786432;               // 3 * 786432
    float* Ps   = P + 3 * 786432;             // 12 * 24576 = 294912
    int*   cnt  = (int*)(Ps + 294912);        // 16
    int*   off  = cnt + 16;                   // 16 (pad to 48)
    u16*   sb   = (u16*)(off + 48);           // bf16 region (16B aligned)

    u16* t1wh = sb;              u16* t1wl = t1wh + 589824;
    u16* t2wh = t1wl + 589824;   u16* t2wl = t2wh + 589824;
    u16* d1wh = t2wl + 589824;   u16* d1wl = d1wh + 589824;
    u16* d2wh = d1wl + 589824;   u16* d2wl = d2wh + 589824;
    u16* m1wh = d2wl + 589824;   u16* m1wl = m1wh + 196608;
    u16* m2wh = m1wl + 196608;   u16* m2wl = m2wh + 589824;
    u16* pwh  = m2wl + 589824;   u16* pwl  = pwh + 1179648;
    u16* feah = pwl + 1179648;   u16* feal = feah + 262144;
    u16* fm1h = feal + 262144;   u16* fm1l = fm1h + 786432;
    u16* fmh  = fm1l + 786432;   u16* fml  = fmh + 786432;
    u16* xph  = fml + 786432;    u16* xpl  = xph + 12288;
    u16* xch  = xpl + 12288;     u16* xcl  = xch + 24576;
    u16* xth  = xcl + 24576;     u16* xtl  = xth + 12288;

    // L1: mean_partial || meta+viszero || pack (weights + features)
    WPack8 wp;
    wp.d[0] = {t1w, t1wh, t1wl, 768, 768, 768, 1};
    wp.d[1] = {t2w, t2wh, t2wl, 768, 768, 768, 1};
    wp.d[2] = {d1w, d1wh, d1wl, 768, 768, 768, 1};
    wp.d[3] = {d2w, d2wh, d2wl, 768, 768, 768, 1};
    wp.d[4] = {m1w, m1wh, m1wl, 768, 256, 256, 1};
    wp.d[5] = {m2w, m2wh, m2wl, 768, 768, 768, 1};
    wp.d[6] = {pw,  pwh,  pwl,  768, 1536, 1536, 1};
    wp.d[7] = {features + 1, feah, feal, 1024, 256, 257, 0};
    k_front<<<7169, 256, 0, stream>>>(wp, (const float4*)inputs, (float4*)part,
                                      bboxes, cnt, off, att, (f32x4*)vis);

    // L2: mean final -> packed x
    k_mean_final<<<16, 256, 0, stream>>>(part, xph, xpl);

    // L3: small#1 || m1-GEMM (512-thr, 2 waves/SIMD)
    k_phaseA<<<180, 512, 0, stream>>>(xph, xpl, d1wh, d1wl, t1wh, t1wl, Ps,
                                      feah, feal, m1wh, m1wl, P);

    // L4: sepi1 || m1-epilogue (relu, -> fm1)
    k_phaseB<<<396, 256, 0, stream>>>(Ps, d1b, t1b, xch, xcl, P, m1b, fm1h, fm1l);

    // L5: small#2 || m2-GEMM (512-thr)
    k_phaseC<<<180, 512, 0, stream>>>(xch, xcl, d2wh, d2wl, t2wh, t2wl, Ps,
                                      fm1h, fm1l, m2wh, m2wl, P);

    // L6: sepi2 || m2-epilogue (-> fm)
    k_phaseD<<<396, 256, 0, stream>>>(Ps, d2b, t2b, retx, xth, xtl, P, m2b, fmh, fml);

    // L7: pw-GEMM (512-thr, xt-gather half + fm half)
    k_pw<<<144, 512, 0, stream>>>(fmh, fml, pwh, pwl, xth, xtl, bboxes, P);

    // L8: bias + scatter into vis
    k_epi_vis<<<768, 256, 0, stream>>>(P, pb, vis, bboxes, off);
}

// Round 6
// 393.958 us; speedup vs baseline: 1.5422x; 1.0355x over previous
//
#include <hip/hip_runtime.h>

#define B_ 16
#define T_ 4096
#define D_ 768
#define NBOX 1024
#define MAXBB 128
#define DDETR 256

typedef unsigned short u16;
typedef short bf16x8 __attribute__((ext_vector_type(8)));
typedef float f32x4 __attribute__((ext_vector_type(4)));

// round-to-nearest-even fp32 -> bf16 split: f ~= hi + lo (both bf16)
__device__ __forceinline__ void split_bf(float f, u16& h, u16& l) {
    unsigned u = __builtin_bit_cast(unsigned, f);
    unsigned r = u + 0x7fffu + ((u >> 16) & 1u);
    u16 hb = (u16)(r >> 16);
    float hf = __builtin_bit_cast(float, (unsigned)hb << 16);
    float lf = f - hf;
    unsigned ul = __builtin_bit_cast(unsigned, lf);
    unsigned rl = ul + 0x7fffu + ((ul >> 16) & 1u);
    h = hb; l = (u16)(rl >> 16);
}

struct WDesc { const float* src; u16* hi; u16* lo; int N; int K; int stride; int vec; };
struct WPack8 { WDesc d[8]; };

// ================= front kernel: mean_partial || meta+viszero || pack ======
// pack: per-block 16-row x 16-kc tile, LDS transpose, coalesced reads+writes.
__global__ __launch_bounds__(256) void k_front(WPack8 ws,
                                               const float4* __restrict__ in4,
                                               float4* __restrict__ part4,
                                               const int* __restrict__ bboxes,
                                               int* __restrict__ cnt_g, int* __restrict__ off_g,
                                               float* __restrict__ att, f32x4* __restrict__ vis4) {
    __shared__ bf16x8 lh[16][17];
    __shared__ bf16x8 ll[16][17];
    int bx = blockIdx.x;
    int tid = threadIdx.x;
    if (bx < 1024) {
        // mean partial: block (b, c), threads 0..191 active
        if (tid >= 192) return;
        int b = bx >> 6, c = bx & 63;
        const float4* base = in4 + (size_t)b * (T_ * D_ / 4) + (size_t)c * (64 * D_ / 4);
        float4 s = {0.f, 0.f, 0.f, 0.f};
        #pragma unroll 4
        for (int r = 0; r < 64; ++r) {
            float4 v = base[(size_t)r * 192 + tid];
            s.x += v.x; s.y += v.y; s.z += v.z; s.w += v.w;
        }
        part4[(size_t)bx * 192 + tid] = s;
        return;
    }
    if (bx < 2561) {
        int mb = bx - 1024;
        if (mb > 0) {
            int idx = (mb - 1) * 256 + tid;    // < 393216
            vis4[idx] = (f32x4){0.f, 0.f, 0.f, 0.f};
            return;
        }
        __shared__ int cnt[B_];
        __shared__ int off[B_];
        if (tid < B_) cnt[tid] = 0;
        __syncthreads();
        for (int i = tid; i < NBOX; i += 256) atomicAdd(&cnt[bboxes[i * 5]], 1);
        __syncthreads();
        if (tid == 0) {
            int acc = 0;
            for (int b = 0; b < B_; ++b) { off[b] = acc; acc += cnt[b]; }
        }
        __syncthreads();
        if (tid < B_) { cnt_g[tid] = cnt[tid]; off_g[tid] = off[tid]; }
        for (int j = tid; j < B_ * MAXBB; j += 256) {
            int b = j >> 7, p = j & 127;
            att[j] = (p < cnt[b]) ? 1.0f : 0.0f;
        }
        return;
    }
    // weight/feature pack: tile (nt, kg) of 16 rows x 128 cols
    int pidx = bx - 2561;                       // < 2240
    const int dEnd[8] = {288, 576, 864, 1152, 1248, 1536, 2112, 2240};
    int di = 0;
    #pragma unroll
    for (int q = 0; q < 7; ++q) di += (pidx >= dEnd[q]);
    WDesc d = ws.d[di];
    int lb = pidx - (di == 0 ? 0 : dEnd[di - 1]);
    int Kc = d.K >> 3;
    int kg = Kc >> 4;
    int nt = lb / kg, kgi = lb - nt * kg;
    int n0 = nt * 16, kc0 = kgi * 16;
    int n_i = tid >> 4, kc_i = tid & 15;
    const float* s = d.src + (size_t)(n0 + n_i) * d.stride + (kc0 + kc_i) * 8;
    float v[8];
    if (d.vec) {
        f32x4 v0 = *(const f32x4*)s, v1 = *(const f32x4*)(s + 4);
        #pragma unroll
        for (int j = 0; j < 4; ++j) { v[j] = v0[j]; v[4 + j] = v1[j]; }
    } else {
        #pragma unroll
        for (int j = 0; j < 8; ++j) v[j] = s[j];
    }
    bf16x8 hv, lv;
    #pragma unroll
    for (int j = 0; j < 8; ++j) {
        u16 h, l;
        split_bf(v[j], h, l); hv[j] = (short)h; lv[j] = (short)l;
    }
    lh[kc_i][n_i] = hv;
    ll[kc_i][n_i] = lv;
    __syncthreads();
    int kc_o = tid >> 4, n_o = tid & 15;
    size_t off = ((size_t)nt * Kc + kc0 + kc_o) * 128 + n_o * 8;
    *(bf16x8*)(d.hi + off) = lh[kc_o][n_o];
    *(bf16x8*)(d.lo + off) = ll[kc_o][n_o];
}

// ========= device: mean final reduce + pack x -> tiled [kc=96][16][8] ======
__device__ __forceinline__ void dev_mean_final(int b, int t, const float* __restrict__ part,
                                               u16* __restrict__ xph, u16* __restrict__ xpl,
                                               float* xm) {
    if (t < 192) {
        f32x4 s = {0.f, 0.f, 0.f, 0.f};
        #pragma unroll 4
        for (int c = 0; c < 64; ++c)
            s += *(const f32x4*)(part + ((size_t)(b * 64 + c)) * 768 + t * 4);
        s *= (1.0f / T_);
        *(f32x4*)(xm + t * 4) = s;
    }
    __syncthreads();
    if (t < 96) {
        const float* p = xm + t * 8;
        bf16x8 hv, lv;
        #pragma unroll
        for (int j = 0; j < 8; ++j) {
            u16 h, l;
            split_bf(p[j], h, l); hv[j] = (short)h; lv[j] = (short)l;
        }
        size_t off = ((size_t)t * 16 + b) * 8;
        *(bf16x8*)(xph + off) = hv;
        *(bf16x8*)(xpl + off) = lv;
    }
}

// ================= device: big MFMA GEMM slice (one-shot K, z=term) ========
// A,W tiled [t16][kc][16][8]. M=1024, N=768. 128x128 block, 4 waves 64x64.
// GATHER=1 (pw): k-steps 0..23 read gathered xt rows ([kc][16][8] by img),
// steps 24..47 read fm tiled (AKc=96).
template<int GATHER>
__device__ __forceinline__ void dev_mfma(const u16* __restrict__ Ahi, const u16* __restrict__ Alo,
                                         const u16* __restrict__ Whi, const u16* __restrict__ Wlo,
                                         const u16* __restrict__ Xth, const u16* __restrict__ Xtl,
                                         const int* __restrict__ bbx,
                                         float* __restrict__ P, int Kc,
                                         int bxn, int byn, int term, int tid) {
    int lane = tid & 63, w = tid >> 6;
    int wm = w >> 1, wn = w & 1;
    int mt0 = byn * 8 + wm * 4;
    int nt0 = bxn * 8 + wn * 4;
    int nk = Kc >> 2;

    const u16* W = (term == 1) ? Wlo : Whi;
    const u16* Wp = W + ((size_t)nt0 * Kc) * 128 + lane * 8;
    size_t wstr = (size_t)Kc * 128;

    const u16* Ab = (term == 2) ? Alo : Ahi;
    const u16* Xb = (term == 2) ? Xtl : Xth;
    int AKc = GATHER ? 96 : Kc;
    size_t aofs[4], xofs[4];
    #pragma unroll
    for (int i = 0; i < 4; ++i)
        aofs[i] = ((size_t)(mt0 + i) * AKc) * 128 + lane * 8;
    if (GATHER) {
        #pragma unroll
        for (int i = 0; i < 4; ++i) {
            int row = (mt0 + i) * 16 + (lane & 15);
            xofs[i] = (size_t)(lane >> 4) * 128 + (size_t)bbx[row * 5] * 8;
        }
    }

    auto LA = [&](int k, bf16x8 (&a)[4]) {
        if (GATHER && k < 24) {
            #pragma unroll
            for (int i = 0; i < 4; ++i)
                a[i] = *(const bf16x8*)(Xb + xofs[i] + (size_t)k * 512);
        } else {
            int kk = GATHER ? k - 24 : k;
            #pragma unroll
            for (int i = 0; i < 4; ++i)
                a[i] = *(const bf16x8*)(Ab + aofs[i] + (size_t)kk * 512);
        }
    };

    bf16x8 a[4], b[4];
    LA(0, a);
    #pragma unroll
    for (int i = 0; i < 4; ++i) b[i] = *(const bf16x8*)(Wp + i * wstr);

    f32x4 acc[16];
    #pragma unroll
    for (int i = 0; i < 16; ++i) acc[i] = (f32x4){0.f, 0.f, 0.f, 0.f};

    for (int k = 0; k < nk; ++k) {
        bf16x8 an[4], bn[4];
        if (k + 1 < nk) {
            LA(k + 1, an);
            #pragma unroll
            for (int i = 0; i < 4; ++i)
                bn[i] = *(const bf16x8*)(Wp + i * wstr + (size_t)(k + 1) * 512);
        }
        #pragma unroll
        for (int i = 0; i < 4; ++i)
            #pragma unroll
            for (int j = 0; j < 4; ++j)
                acc[i * 4 + j] = __builtin_amdgcn_mfma_f32_16x16x32_bf16(a[i], b[j], acc[i * 4 + j], 0, 0, 0);
        #pragma unroll
        for (int i = 0; i < 4; ++i) { a[i] = an[i]; b[i] = bn[i]; }
    }

    float* Pz = P + (size_t)term * (1024 * 768);
    int rb = (lane >> 4) * 4, cb = lane & 15;
    #pragma unroll
    for (int i = 0; i < 4; ++i)
        #pragma unroll
        for (int j = 0; j < 4; ++j) {
            int row = (mt0 + i) * 16 + rb;
            int col = (nt0 + j) * 16 + cb;
            float* p = Pz + (size_t)row * 768 + col;
            f32x4 v = acc[i * 4 + j];
            #pragma unroll
            for (int r = 0; r < 4; ++r) p[(size_t)r * 768] = v[r];
        }
}

// ============ device: big epilogue -> packed bf16 (3-slice reduce) =========
__device__ __forceinline__ void dev_epi_pack(int blk, int tid, int relu,
                                             const float* __restrict__ P,
                                             const float* __restrict__ bias,
                                             u16* __restrict__ dhi, u16* __restrict__ dlo,
                                             int KcDst, int kcOff) {
    int idx = blk * 256 + tid;                  // < 1024*96
    int m = idx / 96, kc = idx - m * 96;
    const float* p0 = P + (size_t)m * 768 + kc * 8;
    f32x4 s0 = *(const f32x4*)p0, s1 = *(const f32x4*)(p0 + 4);
    #pragma unroll
    for (int z = 1; z < 3; ++z) {
        const float* p = p0 + (size_t)z * (1024 * 768);
        s0 += *(const f32x4*)p; s1 += *(const f32x4*)(p + 4);
    }
    s0 += *(const f32x4*)(bias + kc * 8);
    s1 += *(const f32x4*)(bias + kc * 8 + 4);
    bf16x8 hv, lv;
    #pragma unroll
    for (int j = 0; j < 4; ++j) {
        float v0 = relu ? fmaxf(s0[j], 0.f) : s0[j];
        float v1 = relu ? fmaxf(s1[j], 0.f) : s1[j];
        u16 h, l;
        split_bf(v0, h, l); hv[j] = (short)h; lv[j] = (short)l;
        split_bf(v1, h, l); hv[4 + j] = (short)h; lv[4 + j] = (short)l;
    }
    size_t off = ((size_t)(m >> 4) * KcDst + kcOff + kc) * 128 + (m & 15) * 8;
    *(bf16x8*)(dhi + off) = hv;
    *(bf16x8*)(dlo + off) = lv;
}

// ============ big epilogue -> bias + scatter rows directly into vis ========
__global__ __launch_bounds__(256) void k_epi_vis(const float* __restrict__ P,
                                                 const float* __restrict__ bias,
                                                 float* __restrict__ vis,
                                                 const int* __restrict__ bbx,
                                                 const int* __restrict__ off) {
    int idx = blockIdx.x * 256 + threadIdx.x;   // < 1024*192
    int m = idx / 192, c4 = idx - m * 192;
    size_t o = (size_t)m * 768 + c4 * 4;
    f32x4 s = *(const f32x4*)(P + o);
    #pragma unroll
    for (int z = 1; z < 3; ++z) s += *(const f32x4*)(P + (size_t)z * (1024 * 768) + o);
    s += *(const f32x4*)(bias + c4 * 4);
    int b = bbx[m * 5];
    int pp = m - off[b];
    if (pp < MAXBB)
        *(f32x4*)&vis[((size_t)(b * MAXBB + pp)) * 768 + c4 * 4] = s;
}

// ================= device: small-M (M=16) GEMM slice =======================
// combined N=1536 [d|t]. bxn 0..5, z 0..11 (term*4+ks). Kc=96, slice 24.
__device__ __forceinline__ void dev_small(int bxn, int z, int tid,
                                          const u16* __restrict__ A0h, const u16* __restrict__ A0l,
                                          const u16* __restrict__ A1h, const u16* __restrict__ A1l,
                                          const u16* __restrict__ W0h, const u16* __restrict__ W0l,
                                          const u16* __restrict__ W1h, const u16* __restrict__ W1l,
                                          float* __restrict__ Ps) {
    int term = z >> 2, ks = z & 3;
    int lane = tid & 63, w = tid >> 6;
    int nt0 = bxn * 16 + w * 4;                  // global n-tile 0..95
    int path = nt0 >= 48;
    int ntp = nt0 - path * 48;
    const u16* Ah = path ? A1h : A0h;
    const u16* Al = path ? A1l : A0l;
    const u16* Wh = path ? W1h : W0h;
    const u16* Wl = path ? W1l : W0l;
    const u16* A = (term == 2) ? Al : Ah;
    const u16* W = (term == 1) ? Wl : Wh;
    int kc0 = ks * 24;

    const u16* Ap = A + (size_t)kc0 * 128 + lane * 8;
    const u16* Wp = W + ((size_t)ntp * 96 + kc0) * 128 + lane * 8;

    f32x4 acc[4];
    #pragma unroll
    for (int i = 0; i < 4; ++i) acc[i] = (f32x4){0.f, 0.f, 0.f, 0.f};

    #pragma unroll
    for (int k = 0; k < 6; ++k) {
        bf16x8 a = *(const bf16x8*)(Ap + (size_t)k * 512);
        bf16x8 b[4];
        #pragma unroll
        for (int j = 0; j < 4; ++j)
            b[j] = *(const bf16x8*)(Wp + (size_t)j * 96 * 128 + (size_t)k * 512);
        #pragma unroll
        for (int j = 0; j < 4; ++j)
            acc[j] = __builtin_amdgcn_mfma_f32_16x16x32_bf16(a, b[j], acc[j], 0, 0, 0);
    }

    float* Pz = Ps + (size_t)z * (16 * 1536);
    int rb = (lane >> 4) * 4, cb = lane & 15;
    #pragma unroll
    for (int j = 0; j < 4; ++j) {
        int col = (nt0 + j) * 16 + cb;
        float* p = Pz + (size_t)rb * 1536 + col;
        f32x4 v = acc[j];
        #pragma unroll
        for (int r = 0; r < 4; ++r) p[(size_t)r * 1536] = v[r];
    }
}

// ============ device: small epilogue 1 (relu -> xc packed) =================
__device__ __forceinline__ void dev_sepi1(int blk, int tid,
                                          const float* __restrict__ Ps,
                                          const float* __restrict__ d1b, const float* __restrict__ t1b,
                                          u16* __restrict__ xh, u16* __restrict__ xl) {
    int idx = blk * 256 + tid;                   // < 16*192
    int r = idx / 192, cc = idx - r * 192;
    size_t base = (size_t)r * 1536 + cc * 8;
    f32x4 s0 = {0,0,0,0}, s1 = {0,0,0,0};
    for (int z = 0; z < 12; ++z) {
        const float* p = Ps + (size_t)z * (16 * 1536) + base;
        s0 += *(const f32x4*)p; s1 += *(const f32x4*)(p + 4);
    }
    int path = cc >= 96;
    int ccp = cc - path * 96;
    const float* bias = (path ? t1b : d1b) + ccp * 8;
    s0 += *(const f32x4*)bias;
    s1 += *(const f32x4*)(bias + 4);
    bf16x8 hv, lv;
    #pragma unroll
    for (int j = 0; j < 4; ++j) {
        u16 h, l;
        split_bf(fmaxf(s0[j], 0.f), h, l); hv[j] = (short)h; lv[j] = (short)l;
        split_bf(fmaxf(s1[j], 0.f), h, l); hv[4 + j] = (short)h; lv[4 + j] = (short)l;
    }
    size_t off = (size_t)path * 12288 + (size_t)ccp * 128 + r * 8;
    *(bf16x8*)(xh + off) = hv;
    *(bf16x8*)(xl + off) = lv;
}

// ===== device: small epilogue 2 (d -> retx fp32, t -> xt packed) ===========
__device__ __forceinline__ void dev_sepi2(int blk, int tid,
                                          const float* __restrict__ Ps,
                                          const float* __restrict__ d2b, const float* __restrict__ t2b,
                                          float* __restrict__ retx,
                                          u16* __restrict__ xth, u16* __restrict__ xtl) {
    int idx = blk * 256 + tid;                   // < 16*192
    int r = idx / 192, cc = idx - r * 192;
    size_t base = (size_t)r * 1536 + cc * 8;
    f32x4 s0 = {0,0,0,0}, s1 = {0,0,0,0};
    for (int z = 0; z < 12; ++z) {
        const float* p = Ps + (size_t)z * (16 * 1536) + base;
        s0 += *(const f32x4*)p; s1 += *(const f32x4*)(p + 4);
    }
    int path = cc >= 96;
    int ccp = cc - path * 96;
    const float* bias = (path ? t2b : d2b) + ccp * 8;
    s0 += *(const f32x4*)bias;
    s1 += *(const f32x4*)(bias + 4);
    if (!path) {
        float* o = retx + (size_t)r * 768 + ccp * 8;
        *(f32x4*)o = s0;
        *(f32x4*)(o + 4) = s1;
    } else {
        bf16x8 hv, lv;
        #pragma unroll
        for (int j = 0; j < 4; ++j) {
            u16 h, l;
            split_bf(s0[j], h, l); hv[j] = (short)h; lv[j] = (short)l;
            split_bf(s1[j], h, l); hv[4 + j] = (short)h; lv[4 + j] = (short)l;
        }
        size_t off = (size_t)ccp * 128 + r * 8;
        *(bf16x8*)(xth + off) = hv;
        *(bf16x8*)(xtl + off) = lv;
    }
}

// ================= phase kernels (re-bucketed dependencies) ================
// phase A: mean_final (16) || m1-GEMM (144, Kc=32 one-shot)
__global__ __launch_bounds__(256) void k_phaseA(const float* part,
                                                u16* xph, u16* xpl,
                                                const u16* feah, const u16* feal,
                                                const u16* m1wh, const u16* m1wl,
                                                float* P) {
    __shared__ float xm[768];
    int bx = blockIdx.x, tid = threadIdx.x;
    if (bx < 16) {
        dev_mean_final(bx, tid, part, xph, xpl, xm);
    } else {
        int i = bx - 16;
        dev_mfma<0>(feah, feal, m1wh, m1wl, nullptr, nullptr, nullptr,
                    P, 32, i % 6, (i / 6) % 8, i / 48, tid);
    }
}

// phase B: small1 (72) || m1 epilogue -> fm1 packed (384)
__global__ __launch_bounds__(256) void k_phaseB(const u16* xph, const u16* xpl,
                                                const u16* d1wh, const u16* d1wl,
                                                const u16* t1wh, const u16* t1wl,
                                                float* Ps,
                                                const float* P, const float* m1b,
                                                u16* fm1h, u16* fm1l) {
    int bx = blockIdx.x, tid = threadIdx.x;
    if (bx < 72)
        dev_small(bx % 6, bx / 6, tid, xph, xpl, xph, xpl,
                  d1wh, d1wl, t1wh, t1wl, Ps);
    else
        dev_epi_pack(bx - 72, tid, 1, P, m1b, fm1h, fm1l, 96, 0);
}

// phase C: sepi1 (12) || m2-GEMM (144, Kc=96 one-shot)
__global__ __launch_bounds__(256) void k_phaseC(const float* Ps,
                                                const float* d1b, const float* t1b,
                                                u16* xch, u16* xcl,
                                                const u16* fm1h, const u16* fm1l,
                                                const u16* m2wh, const u16* m2wl,
                                                float* P) {
    int bx = blockIdx.x, tid = threadIdx.x;
    if (bx < 12) {
        dev_sepi1(bx, tid, Ps, d1b, t1b, xch, xcl);
    } else {
        int i = bx - 12;
        dev_mfma<0>(fm1h, fm1l, m2wh, m2wl, nullptr, nullptr, nullptr,
                    P, 96, i % 6, (i / 6) % 8, i / 48, tid);
    }
}

// phase D: small2 (72) || m2 epilogue -> fm packed (384)
__global__ __launch_bounds__(256) void k_phaseD(const u16* xch, const u16* xcl,
                                                const u16* d2wh, const u16* d2wl,
                                                const u16* t2wh, const u16* t2wl,
                                                float* Ps,
                                                const float* P, const float* m2b,
                                                u16* fmh, u16* fml) {
    int bx = blockIdx.x, tid = threadIdx.x;
    if (bx < 72)
        dev_small(bx % 6, bx / 6, tid, xch, xcl, xch + 12288, xcl + 12288,
                  d2wh, d2wl, t2wh, t2wl, Ps);
    else
        dev_epi_pack(bx - 72, tid, 0, P, m2b, fmh, fml, 96, 0);
}

// phase E: sepi2 (12) -> retx | xt
__global__ __launch_bounds__(256) void k_phaseE(const float* Ps,
                                                const float* d2b, const float* t2b,
                                                float* retx, u16* xth, u16* xtl) {
    dev_sepi2(blockIdx.x, threadIdx.x, Ps, d2b, t2b, retx, xth, xtl);
}

// pw GEMM: one-shot K=192 per term, xt-gather for first half
__global__ __launch_bounds__(256) void k_pw(const u16* fmh, const u16* fml,
                                            const u16* pwh, const u16* pwl,
                                            const u16* xth, const u16* xtl,
                                            const int* bbx, float* P) {
    int i = blockIdx.x, tid = threadIdx.x;
    dev_mfma<1>(fmh, fml, pwh, pwl, xth, xtl, bbx,
                P, 192, i % 6, (i / 6) % 8, i / 48, tid);
}

extern "C" void kernel_launch(void* const* d_in, const int* in_sizes, int n_in,
                              void* d_out, int out_size, void* d_ws, size_t ws_size,
                              hipStream_t stream) {
    const float* inputs   = (const float*)d_in[0];
    const int*   bboxes   = (const int*)d_in[1];
    const float* features = (const float*)d_in[2];
    const float* t1w = (const float*)d_in[3];
    const float* t1b = (const float*)d_in[4];
    const float* t2w = (const float*)d_in[5];
    const float* t2b = (const float*)d_in[6];
    const float* d1w = (const float*)d_in[7];
    const float* d1b = (const float*)d_in[8];
    const float* d2w = (const float*)d_in[9];
    const float* d2b = (const float*)d_in[10];
    const float* m1w = (const float*)d_in[11];
    const float* m1b = (const float*)d_in[12];
    const float* m2w = (const float*)d_in[13];
    const float* m2b = (const float*)d_in[14];
    const float* pw  = (const float*)d_in[15];
    const float* pb  = (const float*)d_in[16];

    float* out  = (float*)d_out;
    float* vis  = out;                       // 16*128*768
    float* att  = out + 1572864;             // 2048
    float* retx = out + 1574912;             // 12288

    // ---- workspace layout (floats) ----
    float* wsf  = (float*)d_ws;
    float* part = wsf;                        // 786432
    float* P    = wsf + 786432;               // 3 * 786432
    float* Ps   = P + 3 * 786432;             // 12 * 24576 = 294912
    int*   cnt  = (int*)(Ps + 294912);        // 16
    int*   off  = cnt + 16;                   // 16 (pad to 48)
    u16*   sb   = (u16*)(off + 48);           // bf16 region (16B aligned)

    u16* t1wh = sb;              u16* t1wl = t1wh + 589824;
    u16* t2wh = t1wl + 589824;   u16* t2wl = t2wh + 589824;
    u16* d1wh = t2wl + 589824;   u16* d1wl = d1wh + 589824;
    u16* d2wh = d1wl + 589824;   u16* d2wl = d2wh + 589824;
    u16* m1wh = d2wl + 589824;   u16* m1wl = m1wh + 196608;
    u16* m2wh = m1wl + 196608;   u16* m2wl = m2wh + 589824;
    u16* pwh  = m2wl + 589824;   u16* pwl  = pwh + 1179648;
    u16* feah = pwl + 1179648;   u16* feal = feah + 262144;
    u16* fm1h = feal + 262144;   u16* fm1l = fm1h + 786432;
    u16* fmh  = fm1l + 786432;   u16* fml  = fmh + 786432;
    u16* xph  = fml + 786432;    u16* xpl  = xph + 12288;
    u16* xch  = xpl + 12288;     u16* xcl  = xch + 24576;
    u16* xth  = xcl + 24576;     u16* xtl  = xth + 12288;

    // L1: mean_partial || meta+viszero || pack (weights + features, tiled)
    // pack blocks per desc: d0-d3: 288 each, m1w: 96, m2w: 288, pw: 576, feat: 128
    WPack8 wp;
    wp.d[0] = {t1w, t1wh, t1wl, 768, 768, 768, 1};
    wp.d[1] = {t2w, t2wh, t2wl, 768, 768, 768, 1};
    wp.d[2] = {d1w, d1wh, d1wl, 768, 768, 768, 1};
    wp.d[3] = {d2w, d2wh, d2wl, 768, 768, 768, 1};
    wp.d[4] = {m1w, m1wh, m1wl, 768, 256, 256, 1};
    wp.d[5] = {m2w, m2wh, m2wl, 768, 768, 768, 1};
    wp.d[6] = {pw,  pwh,  pwl,  768, 1536, 1536, 1};
    wp.d[7] = {features + 1, feah, feal, 1024, 256, 257, 0};
    k_front<<<4801, 256, 0, stream>>>(wp, (const float4*)inputs, (float4*)part,
                                      bboxes, cnt, off, att, (f32x4*)vis);

    // L2: mean_final || m1-GEMM
    k_phaseA<<<160, 256, 0, stream>>>(part, xph, xpl, feah, feal, m1wh, m1wl, P);

    // L3: small#1 || m1-epilogue (relu, -> fm1)
    k_phaseB<<<456, 256, 0, stream>>>(xph, xpl, d1wh, d1wl, t1wh, t1wl, Ps,
                                      P, m1b, fm1h, fm1l);

    // L4: sepi1 || m2-GEMM
    k_phaseC<<<156, 256, 0, stream>>>(Ps, d1b, t1b, xch, xcl,
                                      fm1h, fm1l, m2wh, m2wl, P);

    // L5: small#2 || m2-epilogue (-> fm)
    k_phaseD<<<456, 256, 0, stream>>>(xch, xcl, d2wh, d2wl, t2wh, t2wl, Ps,
                                      P, m2b, fmh, fml);

    // L6: sepi2 (-> retx | xt)
    k_phaseE<<<12, 256, 0, stream>>>(Ps, d2b, t2b, retx, xth, xtl);

    // L7: pw-GEMM (xt-gather half + fm half)
    k_pw<<<144, 256, 0, stream>>>(fmh, fml, pwh, pwl, xth, xtl, bboxes, P);

    // L8: bias + scatter into vis
    k_epi_vis<<<768, 256, 0, stream>>>(P, pb, vis, bboxes, off);
}